// Round 1
// baseline (232.208 us; speedup 1.0000x reference)
//
#include <hip/hip_runtime.h>
#include <stdint.h>

// MultiBoxLoss: B=64 rows, D=65536 anchors, ~2% positives.
// R8: single-launch fusion. rocprof showed the timed region is dominated by
// harness 256MiB workspace poison fills (~40us each at 83% HBM peak); our own
// three kernels are each <40us and sum to ~25us. The only lever we still own
// is launch count and the two grid-wide serializations, so k1/ksel/k5 are
// fused into ONE kernel using last-arriving-block elections:
//   - each of 1024 blocks does its k1 chunk, then acq_rel(AGENT) fetch_add on
//     its row counter; the 16th block of a row runs that row's exact top-k
//     (overlapping rows' ksel with other rows' k1 work),
//   - the 64th row-finisher runs the final scalar reduction.
// No spinning -> no co-residency assumption, no deadlock risk. Cross-XCD
// visibility via __hip_atomic ACQ_REL at AGENT scope (+ __syncthreads vmcnt
// drain before the release publishes block-wide writes).
// ksel now reads candidates directly from global (L2/L3-resident, ~28KB/row
// x2 passes) instead of staging lval[8192] in LDS: kills the n>LCAP fallback
// and keeps fused LDS at ~25KB (union with k1's lcand/lpos).
// Counters must be zeroed per iteration (ws is poisoned): 260-byte
// hipMemsetAsync (graph-capturable; harness itself enqueues memsets).

#define B_ 64
#define D_ 65536
#define NEGPOS 3
#define BPR 16                 // blocks per row
#define NBLK (B_ * BPR)        // 1024
#define CHUNK (D_ / BPR)       // 4096 elements per block
#define XC 1.25f               // candidate cutoff (P(x>=XC)~10.6% per row)
#define HBINS 4096             // histogram bins over x in [XC, XC+XRANGE)
#define XRANGE 5.0f
#define CJCAP 1024             // bin-J gather capacity (expect ~8)

// ---------------- ws layout (bytes) ----------------
#define OFF_SL1P     0                      // double[NBLK]
#define OFF_BCEP     8192                   // double[NBLK]
#define OFF_NP       16384                  // u32[NBLK]
#define OFF_CC       20480                  // u32[NBLK]
#define OFF_NEGSUM   24576                  // double[64]
#define OFF_KSEL     25088                  // int[64]
#define OFF_CNT      25344                  // u32 rowcnt[64] + u32 donecnt  (ZEROED per iter)
#define OFF_CAND     32768                  // float[NBLK][CHUNK] = 16 MiB

__device__ __forceinline__ float softplus_f(float x) {   // bce for t=0
    return fmaxf(x, 0.0f) + log1pf(expf(-fabsf(x)));
}

__device__ __forceinline__ int bin_of_x(float x) {
    int b = (int)((x - XC) * ((float)HBINS / XRANGE));
    return max(0, min(HBINS - 1, b));
}

__device__ __forceinline__ float smooth_l1_4(float4 a, float4 b) {
    float s = 0.0f, d, ad;
    d = a.x - b.x; ad = fabsf(d); s += (ad < 1.0f) ? 0.5f * d * d : ad - 0.5f;
    d = a.y - b.y; ad = fabsf(d); s += (ad < 1.0f) ? 0.5f * d * d : ad - 0.5f;
    d = a.z - b.z; ad = fabsf(d); s += (ad < 1.0f) ? 0.5f * d * d : ad - 0.5f;
    d = a.w - b.w; ad = fabsf(d); s += (ad < 1.0f) ? 0.5f * d * d : ad - 0.5f;
    return s;
}

__device__ __forceinline__ double wredD(double v) {
#pragma unroll
    for (int o = 32; o > 0; o >>= 1) v += __shfl_down(v, o, 64);
    return v;
}
__device__ __forceinline__ int wredI(int v) {
#pragma unroll
    for (int o = 32; o > 0; o >>= 1) v += __shfl_down(v, o, 64);
    return v;
}

__device__ __forceinline__ int blockSumI(int v, int* sh) {
    int w = wredI(v);
    const int lane = threadIdx.x & 63, wid = threadIdx.x >> 6;
    __syncthreads();
    if (lane == 0) sh[wid] = w;
    __syncthreads();
    return sh[0] + sh[1] + sh[2] + sh[3];
}

__global__ void __launch_bounds__(256)
mbl_fused(const float4* __restrict__ loc4, const float* __restrict__ conf,
          const float4* __restrict__ loct4, const int* __restrict__ conft,
          unsigned char* __restrict__ ws, float* __restrict__ out)
{
    // k1 phase needs lcand+lpos (24KB); ksel phase needs hist+ubuf (20KB).
    // Never live at the same time -> union keeps LDS at ~25KB (6 blk/CU cap,
    // grid gives 4/CU anyway).
    __shared__ union {
        struct { float lcand[CHUNK]; unsigned short lpos[CHUNK]; } a;
        struct { unsigned hist[HBINS]; float ubuf[CJCAP]; } b;
    } u;
    __shared__ unsigned wtot[4];
    __shared__ double wr[8];
    __shared__ double wrC[4];
    __shared__ int shN[4], shK[4];
    __shared__ unsigned segoff[BPR + 1], sccS[BPR], wsuf[4];
    __shared__ unsigned shJ, shRemJ, shCj, shNP;
    __shared__ int shI[4];
    __shared__ int shLast;

    const int block = blockIdx.x;
    const int row = block >> 4;          // BPR = 16
    const int base = block * CHUNK;
    const int lane = threadIdx.x & 63, wid = threadIdx.x >> 6;

    // ===================== Phase A: per-chunk pass (was k1) =====================
    {
        const float4* c4 = (const float4*)(conf + base);
        const int4*   t4 = (const int4*)(conft + base);

        float4 xv[4]; int4 tv[4];
#pragma unroll
        for (int it = 0; it < 4; it++) {
            const int g = threadIdx.x + it * 256;
            xv[it] = c4[g];
            tv[it] = t4[g];
        }

        double bcp = 0.0;
        unsigned cntc = 0, cntp = 0;
#pragma unroll
        for (int it = 0; it < 4; it++) {
#pragma unroll
            for (int c = 0; c < 4; c++) {
                float x = (c == 0) ? xv[it].x : (c == 1) ? xv[it].y : (c == 2) ? xv[it].z : xv[it].w;
                int   t = (c == 0) ? tv[it].x : (c == 1) ? tv[it].y : (c == 2) ? tv[it].z : tv[it].w;
                if (t > 0) { cntp++; bcp += (double)(softplus_f(x) - x); }
                else if (x >= XC) cntc++;
            }
        }

        unsigned pk = (cntc << 16) | cntp;
        unsigned incl = pk;
#pragma unroll
        for (int o = 1; o < 64; o <<= 1) {
            unsigned v = __shfl_up(incl, o, 64);
            if (lane >= o) incl += v;
        }
        unsigned excl = incl - pk;
        if (lane == 63) wtot[wid] = incl;
        __syncthreads();
        unsigned wbase = 0;
        for (int w = 0; w < wid; w++) wbase += wtot[w];
        const unsigned tot = wtot[0] + wtot[1] + wtot[2] + wtot[3];
        const unsigned totc = tot >> 16, totp = tot & 0xFFFFu;
        unsigned offc = (excl >> 16) + (wbase >> 16);
        unsigned offp = (excl & 0xFFFFu) + (wbase & 0xFFFFu);

#pragma unroll
        for (int it = 0; it < 4; it++) {
#pragma unroll
            for (int c = 0; c < 4; c++) {
                float x = (c == 0) ? xv[it].x : (c == 1) ? xv[it].y : (c == 2) ? xv[it].z : xv[it].w;
                int   t = (c == 0) ? tv[it].x : (c == 1) ? tv[it].y : (c == 2) ? tv[it].z : tv[it].w;
                const int li = (threadIdx.x + it * 256) * 4 + c;
                if (t > 0) u.a.lpos[offp++] = (unsigned short)li;
                else if (x >= XC) u.a.lcand[offc++] = x;
            }
        }
        __syncthreads();

        float* seg = (float*)(ws + OFF_CAND) + (size_t)block * CHUNK;
        for (unsigned i = threadIdx.x; i < totc; i += 256) seg[i] = u.a.lcand[i];

        double sl1 = 0.0;
        for (unsigned i = threadIdx.x; i < totp; i += 256) {
            const int e = base + (int)u.a.lpos[i];
            sl1 += (double)smooth_l1_4(loc4[e], loct4[e]);
        }

        double s1 = wredD(sl1), s2 = wredD(bcp);
        if (lane == 0) { wr[wid] = s1; wr[4 + wid] = s2; }
        __syncthreads();
        if (threadIdx.x == 0) {
            ((double*)(ws + OFF_SL1P))[block] = wr[0] + wr[1] + wr[2] + wr[3];
            ((double*)(ws + OFF_BCEP))[block] = wr[4] + wr[5] + wr[6] + wr[7];
            ((unsigned*)(ws + OFF_NP))[block] = totp;
            ((unsigned*)(ws + OFF_CC))[block] = totc;
        }
    }

    // ---- publish + row-last election. __syncthreads drains every wave's
    // vmcnt (block writes reach L2); the ACQ_REL AGENT RMW flushes/invalidates
    // across XCDs.
    __syncthreads();
    if (threadIdx.x == 0) {
        unsigned old = __hip_atomic_fetch_add(
            (unsigned*)(ws + OFF_CNT) + row, 1u,
            __ATOMIC_ACQ_REL, __HIP_MEMORY_SCOPE_AGENT);
        shLast = (old == BPR - 1) ? 1 : 0;
    }
    __syncthreads();
    if (!shLast) return;

    // ===================== Phase B: row exact top-k (was ksel) =====================
    const unsigned* ccp = (const unsigned*)(ws + OFF_CC) + row * BPR;
    const unsigned* npp = (const unsigned*)(ws + OFF_NP) + row * BPR;

    if (wid == 0) {
        unsigned c = (lane < BPR) ? ccp[lane] : 0u;
        unsigned p = (lane < BPR) ? npp[lane] : 0u;
        unsigned inc = c;
#pragma unroll
        for (int o = 1; o < BPR; o <<= 1) {
            unsigned v = __shfl_up(inc, o, 64);
            if (lane >= o) inc += v;
        }
        unsigned ptot = p;
#pragma unroll
        for (int o = 1; o < BPR; o <<= 1) ptot += __shfl_down(ptot, o, 64);
        if (lane < BPR) { segoff[lane] = inc - c; sccS[lane] = c; }
        if (lane == BPR - 1) segoff[BPR] = inc;
        if (lane == 0) { shNP = ptot; shCj = 0; }
    }
    __syncthreads();

    const int np = (int)shNP;
    const unsigned n = segoff[BPR];
    long long k = (long long)np * NEGPOS;
    if (k > D_) k = D_;
    long long negs = (long long)D_ - np;
    if (k > negs) k = negs;
    if (threadIdx.x == 0) ((int*)(ws + OFF_KSEL))[row] = (int)k;

    bool donesum = false;
    bool needfb = false;
    if (k <= 0) {
        if (threadIdx.x == 0) ((double*)(ws + OFF_NEGSUM))[row] = 0.0;
        donesum = true;
    } else if ((long long)n < k) {
        needfb = true;                    // not enough candidates above XC
    }

    const float* cand = (const float*)(ws + OFF_CAND);

    if (!donesum && !needfb) {
        // zero + build histogram from GLOBAL candidates (16 threads/segment)
        for (int i = threadIdx.x; i < HBINS; i += 256) u.b.hist[i] = 0;
        __syncthreads();
        const int s = threadIdx.x >> 4, li = threadIdx.x & 15;
        const float* gseg = cand + (size_t)(row * BPR + s) * CHUNK;
        const unsigned cs = sccS[s];
        for (unsigned i = li; i < cs; i += 16)
            atomicAdd(&u.b.hist[bin_of_x(gseg[i])], 1u);
        __syncthreads();

        // parallel suffix scan over 4096 bins -> threshold bin J, remJ
        {
            unsigned s16 = 0; const int b0 = threadIdx.x * 16;
#pragma unroll
            for (int i = 0; i < 16; i++) s16 += u.b.hist[b0 + i];
            unsigned suf = s16;
#pragma unroll
            for (int o = 1; o < 64; o <<= 1) {
                unsigned v = __shfl_down(suf, o, 64);
                if (lane + o < 64) suf += v;
            }
            if (lane == 0) wsuf[wid] = suf;
            __syncthreads();
            unsigned add = 0;
            for (int w = wid + 1; w < 4; w++) add += wsuf[w];
            suf += add;                          // inclusive suffix over all 256
            const unsigned sufx = suf - s16;     // bins strictly above my chunk
            if ((long long)sufx < k && (long long)suf >= k) {
                long long cum = sufx;
                for (int b = b0 + 15; b >= b0; b--) {
                    cum += u.b.hist[b];
                    if (cum >= k) {
                        shJ = (unsigned)b;
                        shRemJ = (unsigned)(k - (cum - (long long)u.b.hist[b]));
                        break;
                    }
                }
            }
        }
        __syncthreads();
        const unsigned J = shJ, remJ = shRemJ;

        // single pass: sum softplus over bins > J, gather bin-J values (~8)
        double acc = 0.0;
        for (unsigned i = li; i < cs; i += 16) {
            const float x = gseg[i];
            const int b = bin_of_x(x);
            if (b > (int)J) acc += (double)softplus_f(x);
            else if (b == (int)J) {
                unsigned p = atomicAdd(&shCj, 1u);
                if (p < CJCAP) u.b.ubuf[p] = x;
            }
        }
        __syncthreads();
        const unsigned cj = shCj;

        if (cj <= CJCAP) {
            // exact rank-select of top-remJ inside bin J (ties by index)
            for (unsigned i = threadIdx.x; i < cj; i += 256) {
                const float xi = u.b.ubuf[i];
                unsigned r = 0;
                for (unsigned l = 0; l < cj; l++) {
                    const float xl = u.b.ubuf[l];
                    r += (xl > xi || (xl == xi && l < i)) ? 1u : 0u;
                }
                if (r < remJ) acc += (double)softplus_f(xi);
            }
            double t = wredD(acc);
            if (lane == 0) wr[wid] = t;
            __syncthreads();
            if (threadIdx.x == 0)
                ((double*)(ws + OFF_NEGSUM))[row] = wr[0] + wr[1] + wr[2] + wr[3];
            donesum = true;
        } else {
            needfb = true;    // pathological mass-tie: fall back to bisection
        }
    }

    if (!donesum && needfb) {
        // exact uint-bisection over the full row (bit-exact threshold)
        const float* rowc = conf + row * D_;
        const int*   rowt = conft + row * D_;
        unsigned lo = 0u, hi = 0xFFFFFFFFu;
        for (int it = 0; it < 32; it++) {
            const unsigned mid = lo + ((hi - lo) >> 1);
            unsigned um = (mid & 0x80000000u) ? (mid & 0x7FFFFFFFu) : ~mid;
            float fm = __uint_as_float(um);
            int c = 0;
            for (int i = threadIdx.x; i < D_; i += 256)
                if (rowt[i] <= 0 && rowc[i] > fm) c++;
            const int tot = blockSumI(c, shI);
            if ((long long)tot >= k) lo = mid; else hi = mid;
        }
        unsigned uT = (hi & 0x80000000u) ? (hi & 0x7FFFFFFFu) : ~hi;
        float xT = __uint_as_float(uT);
        int c = 0;
        double acc = 0.0;
        for (int i = threadIdx.x; i < D_; i += 256) {
            if (rowt[i] <= 0) {
                float x = rowc[i];
                if (x > xT) { c++; acc += (double)softplus_f(x); }
            }
        }
        int rem = (int)(k - (long long)blockSumI(c, shI));
        double t = wredD(acc);
        if (lane == 0) wr[wid] = t;
        __syncthreads();
        if (threadIdx.x == 0)
            ((double*)(ws + OFF_NEGSUM))[row] =
                wr[0] + wr[1] + wr[2] + wr[3] +
                (double)rem * (double)softplus_f(xT);
    }

    // ---- done-row election
    __syncthreads();
    if (threadIdx.x == 0) {
        unsigned old = __hip_atomic_fetch_add(
            (unsigned*)(ws + OFF_CNT) + B_, 1u,
            __ATOMIC_ACQ_REL, __HIP_MEMORY_SCOPE_AGENT);
        shLast = (old == B_ - 1) ? 1 : 0;
    }
    __syncthreads();
    if (!shLast) return;

    // ===================== Phase C: final reduce (was k5) =====================
    {
        const double* sl1p = (const double*)(ws + OFF_SL1P);
        const double* bcep = (const double*)(ws + OFF_BCEP);
        const unsigned* npb = (const unsigned*)(ws + OFF_NP);
        const int* kselp = (const int*)(ws + OFF_KSEL);
        const double* nsp = (const double*)(ws + OFF_NEGSUM);

        double a = 0.0, b2 = 0.0, c2 = 0.0;
        int nn = 0, kk = 0;
        for (int i = threadIdx.x; i < NBLK; i += 256) {
            a += sl1p[i]; b2 += bcep[i]; nn += (int)npb[i];
        }
        if (threadIdx.x < B_) { kk = kselp[threadIdx.x]; c2 = nsp[threadIdx.x]; }

        double ra = wredD(a), rb = wredD(b2), rc = wredD(c2);
        int rn = wredI(nn), rk = wredI(kk);
        if (lane == 0) { wr[wid] = ra; wr[4 + wid] = rb; wrC[wid] = rc; shN[wid] = rn; shK[wid] = rk; }
        __syncthreads();
        if (threadIdx.x == 0) {
            double SL1 = wr[0] + wr[1] + wr[2] + wr[3];
            double BCE = wr[4] + wr[5] + wr[6] + wr[7];
            double NSUM = wrC[0] + wrC[1] + wrC[2] + wrC[3];
            double Np = (double)(shN[0] + shN[1] + shN[2] + shN[3]);
            double Kt = (double)(shK[0] + shK[1] + shK[2] + shK[3]);
            double out0 = (Np > 0.0) ? (SL1 / (4.0 * Np)) / Np : 0.0;
            double denom = Np + Kt;
            double out1 = (Np > 0.0 && denom > 0.0) ? ((BCE + NSUM) / denom) / Np : 0.0;
            out[0] = (float)out0;
            out[1] = (float)out1;
        }
    }
}

extern "C" void kernel_launch(void* const* d_in, const int* in_sizes, int n_in,
                              void* d_out, int out_size, void* d_ws, size_t ws_size,
                              hipStream_t stream)
{
    const float4* loc4  = (const float4*)d_in[0];   // (B,D,4) f32
    const float*  conf  = (const float*)d_in[1];    // (B,D,1) f32
    const float4* loct4 = (const float4*)d_in[2];   // (B,D,4) f32
    const int*    conft = (const int*)d_in[3];      // (B,D)   i32
    unsigned char* ws = (unsigned char*)d_ws;
    float* out = (float*)d_out;

    // zero the 65 election counters (ws is poisoned each iteration)
    hipMemsetAsync(ws + OFF_CNT, 0, (B_ + 1) * sizeof(unsigned), stream);
    mbl_fused<<<dim3(NBLK), dim3(256), 0, stream>>>(loc4, conf, loct4, conft, ws, out);
}

// Round 2
// 194.170 us; speedup vs baseline: 1.1959x; 1.1959x over previous
//
#include <hip/hip_runtime.h>
#include <stdint.h>

// MultiBoxLoss: B=64 rows, D=65536 anchors, ~2% positives.
// R9: fusion kept, coherence rebuilt. R8's ACQ_REL AGENT elections emitted
// cache-wide buffer_wbl2/buffer_inv around EVERY counter RMW (1088 of them)
// -> ~100us of serialized whole-L2 writeback/invalidate (kernel 109us, all
// pipes idle: HBM 3.4%, VALU 12%). Fix: RELAXED agent-scope atomics and
// sc0/sc1 per-instruction coherence for the inter-block data:
//   - all cross-block data (CAND, SL1P, BCEP, NP, CC, KSEL, NEGSUM) is
//     written with __hip_atomic_store(RELAXED, AGENT) -> global_store sc0 sc1
//     (write-through to Infinity Cache, no dirty L2 lines, no wbl2 needed),
//   - read with __hip_atomic_load(RELAXED, AGENT) -> global_load sc0 sc1
//     (bypasses the reader's L2, hits L3),
//   - elections are RELAXED fetch_add (global_atomic sc1, no cache ops).
// Ordering: the __syncthreads() before each election drains vmcnt(0) for all
// waves (compiler emits full s_waitcnt before s_barrier), so the sc1 data is
// at L3 before the counter RMW lands at L3; the elected finisher that sees
// the final count reads the data from L3. No cache-wide ops anywhere.
// Counters zeroed per iteration via 260-byte hipMemsetAsync (ws is poisoned).

#define B_ 64
#define D_ 65536
#define NEGPOS 3
#define BPR 16                 // blocks per row
#define NBLK (B_ * BPR)        // 1024
#define CHUNK (D_ / BPR)       // 4096 elements per block
#define XC 1.25f               // candidate cutoff (P(x>=XC)~10.6% per row)
#define HBINS 4096             // histogram bins over x in [XC, XC+XRANGE)
#define XRANGE 5.0f
#define CJCAP 1024             // bin-J gather capacity (expect ~8)

// ---------------- ws layout (bytes) ----------------
#define OFF_SL1P     0                      // double[NBLK]
#define OFF_BCEP     8192                   // double[NBLK]
#define OFF_NP       16384                  // u32[NBLK]
#define OFF_CC       20480                  // u32[NBLK]
#define OFF_NEGSUM   24576                  // double[64]
#define OFF_KSEL     25088                  // int[64]
#define OFF_CNT      25344                  // u32 rowcnt[64] + u32 donecnt  (ZEROED per iter)
#define OFF_CAND     32768                  // float[NBLK][CHUNK] = 16 MiB

// ---- agent-coherent (sc0 sc1) relaxed memory ops: per-instruction
// coherence, NO cache-wide wbl2/inv (those come only from acq/rel orderings).
__device__ __forceinline__ void stgF(float* p, float v) {
    __hip_atomic_store(p, v, __ATOMIC_RELAXED, __HIP_MEMORY_SCOPE_AGENT);
}
__device__ __forceinline__ void stgU(unsigned* p, unsigned v) {
    __hip_atomic_store(p, v, __ATOMIC_RELAXED, __HIP_MEMORY_SCOPE_AGENT);
}
__device__ __forceinline__ void stgI(int* p, int v) {
    __hip_atomic_store(p, v, __ATOMIC_RELAXED, __HIP_MEMORY_SCOPE_AGENT);
}
__device__ __forceinline__ void stgD(double* p, double v) {
    __hip_atomic_store(p, v, __ATOMIC_RELAXED, __HIP_MEMORY_SCOPE_AGENT);
}
__device__ __forceinline__ float ldgF(const float* p) {
    return __hip_atomic_load(p, __ATOMIC_RELAXED, __HIP_MEMORY_SCOPE_AGENT);
}
__device__ __forceinline__ unsigned ldgU(const unsigned* p) {
    return __hip_atomic_load(p, __ATOMIC_RELAXED, __HIP_MEMORY_SCOPE_AGENT);
}
__device__ __forceinline__ int ldgI(const int* p) {
    return __hip_atomic_load(p, __ATOMIC_RELAXED, __HIP_MEMORY_SCOPE_AGENT);
}
__device__ __forceinline__ double ldgD(const double* p) {
    return __hip_atomic_load(p, __ATOMIC_RELAXED, __HIP_MEMORY_SCOPE_AGENT);
}

__device__ __forceinline__ float softplus_f(float x) {   // bce for t=0
    return fmaxf(x, 0.0f) + log1pf(expf(-fabsf(x)));
}

__device__ __forceinline__ int bin_of_x(float x) {
    int b = (int)((x - XC) * ((float)HBINS / XRANGE));
    return max(0, min(HBINS - 1, b));
}

__device__ __forceinline__ float smooth_l1_4(float4 a, float4 b) {
    float s = 0.0f, d, ad;
    d = a.x - b.x; ad = fabsf(d); s += (ad < 1.0f) ? 0.5f * d * d : ad - 0.5f;
    d = a.y - b.y; ad = fabsf(d); s += (ad < 1.0f) ? 0.5f * d * d : ad - 0.5f;
    d = a.z - b.z; ad = fabsf(d); s += (ad < 1.0f) ? 0.5f * d * d : ad - 0.5f;
    d = a.w - b.w; ad = fabsf(d); s += (ad < 1.0f) ? 0.5f * d * d : ad - 0.5f;
    return s;
}

__device__ __forceinline__ double wredD(double v) {
#pragma unroll
    for (int o = 32; o > 0; o >>= 1) v += __shfl_down(v, o, 64);
    return v;
}
__device__ __forceinline__ int wredI(int v) {
#pragma unroll
    for (int o = 32; o > 0; o >>= 1) v += __shfl_down(v, o, 64);
    return v;
}

__device__ __forceinline__ int blockSumI(int v, int* sh) {
    int w = wredI(v);
    const int lane = threadIdx.x & 63, wid = threadIdx.x >> 6;
    __syncthreads();
    if (lane == 0) sh[wid] = w;
    __syncthreads();
    return sh[0] + sh[1] + sh[2] + sh[3];
}

__global__ void __launch_bounds__(256)
mbl_fused(const float4* __restrict__ loc4, const float* __restrict__ conf,
          const float4* __restrict__ loct4, const int* __restrict__ conft,
          unsigned char* __restrict__ ws, float* __restrict__ out)
{
    // k1 phase needs lcand+lpos (24KB); ksel phase needs hist+ubuf (20KB).
    // Never live at the same time -> union keeps LDS at ~25KB.
    __shared__ union {
        struct { float lcand[CHUNK]; unsigned short lpos[CHUNK]; } a;
        struct { unsigned hist[HBINS]; float ubuf[CJCAP]; } b;
    } u;
    __shared__ unsigned wtot[4];
    __shared__ double wr[8];
    __shared__ double wrC[4];
    __shared__ int shN[4], shK[4];
    __shared__ unsigned segoff[BPR + 1], sccS[BPR], wsuf[4];
    __shared__ unsigned shJ, shRemJ, shCj, shNP;
    __shared__ int shI[4];
    __shared__ int shLast;

    const int block = blockIdx.x;
    const int row = block >> 4;          // BPR = 16
    const int base = block * CHUNK;
    const int lane = threadIdx.x & 63, wid = threadIdx.x >> 6;

    // ===================== Phase A: per-chunk pass (was k1) =====================
    {
        const float4* c4 = (const float4*)(conf + base);
        const int4*   t4 = (const int4*)(conft + base);

        float4 xv[4]; int4 tv[4];
#pragma unroll
        for (int it = 0; it < 4; it++) {
            const int g = threadIdx.x + it * 256;
            xv[it] = c4[g];
            tv[it] = t4[g];
        }

        double bcp = 0.0;
        unsigned cntc = 0, cntp = 0;
#pragma unroll
        for (int it = 0; it < 4; it++) {
#pragma unroll
            for (int c = 0; c < 4; c++) {
                float x = (c == 0) ? xv[it].x : (c == 1) ? xv[it].y : (c == 2) ? xv[it].z : xv[it].w;
                int   t = (c == 0) ? tv[it].x : (c == 1) ? tv[it].y : (c == 2) ? tv[it].z : tv[it].w;
                if (t > 0) { cntp++; bcp += (double)(softplus_f(x) - x); }
                else if (x >= XC) cntc++;
            }
        }

        unsigned pk = (cntc << 16) | cntp;
        unsigned incl = pk;
#pragma unroll
        for (int o = 1; o < 64; o <<= 1) {
            unsigned v = __shfl_up(incl, o, 64);
            if (lane >= o) incl += v;
        }
        unsigned excl = incl - pk;
        if (lane == 63) wtot[wid] = incl;
        __syncthreads();
        unsigned wbase = 0;
        for (int w = 0; w < wid; w++) wbase += wtot[w];
        const unsigned tot = wtot[0] + wtot[1] + wtot[2] + wtot[3];
        const unsigned totc = tot >> 16, totp = tot & 0xFFFFu;
        unsigned offc = (excl >> 16) + (wbase >> 16);
        unsigned offp = (excl & 0xFFFFu) + (wbase & 0xFFFFu);

#pragma unroll
        for (int it = 0; it < 4; it++) {
#pragma unroll
            for (int c = 0; c < 4; c++) {
                float x = (c == 0) ? xv[it].x : (c == 1) ? xv[it].y : (c == 2) ? xv[it].z : xv[it].w;
                int   t = (c == 0) ? tv[it].x : (c == 1) ? tv[it].y : (c == 2) ? tv[it].z : tv[it].w;
                const int li = (threadIdx.x + it * 256) * 4 + c;
                if (t > 0) u.a.lpos[offp++] = (unsigned short)li;
                else if (x >= XC) u.a.lcand[offc++] = x;
            }
        }
        __syncthreads();

        // publish candidates write-through (sc0 sc1): visible at L3, no dirty
        // L2 lines -> no wbl2 ever needed
        float* seg = (float*)(ws + OFF_CAND) + (size_t)block * CHUNK;
        for (unsigned i = threadIdx.x; i < totc; i += 256) stgF(seg + i, u.a.lcand[i]);

        double sl1 = 0.0;
        for (unsigned i = threadIdx.x; i < totp; i += 256) {
            const int e = base + (int)u.a.lpos[i];
            sl1 += (double)smooth_l1_4(loc4[e], loct4[e]);
        }

        double s1 = wredD(sl1), s2 = wredD(bcp);
        if (lane == 0) { wr[wid] = s1; wr[4 + wid] = s2; }
        __syncthreads();
        if (threadIdx.x == 0) {
            stgD((double*)(ws + OFF_SL1P) + block, wr[0] + wr[1] + wr[2] + wr[3]);
            stgD((double*)(ws + OFF_BCEP) + block, wr[4] + wr[5] + wr[6] + wr[7]);
            stgU((unsigned*)(ws + OFF_NP) + block, totp);
            stgU((unsigned*)(ws + OFF_CC) + block, totc);
        }
    }

    // ---- row-last election. The __syncthreads drains every wave's vmcnt
    // (sc1 stores are at L3 by then); the RELAXED agent RMW lands at L3 after.
    __syncthreads();
    if (threadIdx.x == 0) {
        unsigned old = __hip_atomic_fetch_add(
            (unsigned*)(ws + OFF_CNT) + row, 1u,
            __ATOMIC_RELAXED, __HIP_MEMORY_SCOPE_AGENT);
        shLast = (old == BPR - 1) ? 1 : 0;
    }
    __syncthreads();
    if (!shLast) return;

    // ===================== Phase B: row exact top-k (was ksel) =====================
    const unsigned* ccp = (const unsigned*)(ws + OFF_CC) + row * BPR;
    const unsigned* npp = (const unsigned*)(ws + OFF_NP) + row * BPR;

    if (wid == 0) {
        unsigned c = (lane < BPR) ? ldgU(ccp + lane) : 0u;
        unsigned p = (lane < BPR) ? ldgU(npp + lane) : 0u;
        unsigned inc = c;
#pragma unroll
        for (int o = 1; o < BPR; o <<= 1) {
            unsigned v = __shfl_up(inc, o, 64);
            if (lane >= o) inc += v;
        }
        unsigned ptot = p;
#pragma unroll
        for (int o = 1; o < BPR; o <<= 1) ptot += __shfl_down(ptot, o, 64);
        if (lane < BPR) { segoff[lane] = inc - c; sccS[lane] = c; }
        if (lane == BPR - 1) segoff[BPR] = inc;
        if (lane == 0) { shNP = ptot; shCj = 0; }
    }
    __syncthreads();

    const int np = (int)shNP;
    const unsigned n = segoff[BPR];
    long long k = (long long)np * NEGPOS;
    if (k > D_) k = D_;
    long long negs = (long long)D_ - np;
    if (k > negs) k = negs;
    if (threadIdx.x == 0) stgI((int*)(ws + OFF_KSEL) + row, (int)k);

    bool donesum = false;
    bool needfb = false;
    if (k <= 0) {
        if (threadIdx.x == 0) stgD((double*)(ws + OFF_NEGSUM) + row, 0.0);
        donesum = true;
    } else if ((long long)n < k) {
        needfb = true;                    // not enough candidates above XC
    }

    const float* cand = (const float*)(ws + OFF_CAND);

    if (!donesum && !needfb) {
        // zero + build histogram from GLOBAL candidates (16 threads/segment)
        for (int i = threadIdx.x; i < HBINS; i += 256) u.b.hist[i] = 0;
        __syncthreads();
        const int s = threadIdx.x >> 4, li = threadIdx.x & 15;
        const float* gseg = cand + (size_t)(row * BPR + s) * CHUNK;
        const unsigned cs = sccS[s];
        for (unsigned i = li; i < cs; i += 16)
            atomicAdd(&u.b.hist[bin_of_x(ldgF(gseg + i))], 1u);
        __syncthreads();

        // parallel suffix scan over 4096 bins -> threshold bin J, remJ
        {
            unsigned s16 = 0; const int b0 = threadIdx.x * 16;
#pragma unroll
            for (int i = 0; i < 16; i++) s16 += u.b.hist[b0 + i];
            unsigned suf = s16;
#pragma unroll
            for (int o = 1; o < 64; o <<= 1) {
                unsigned v = __shfl_down(suf, o, 64);
                if (lane + o < 64) suf += v;
            }
            if (lane == 0) wsuf[wid] = suf;
            __syncthreads();
            unsigned add = 0;
            for (int w = wid + 1; w < 4; w++) add += wsuf[w];
            suf += add;                          // inclusive suffix over all 256
            const unsigned sufx = suf - s16;     // bins strictly above my chunk
            if ((long long)sufx < k && (long long)suf >= k) {
                long long cum = sufx;
                for (int b = b0 + 15; b >= b0; b--) {
                    cum += u.b.hist[b];
                    if (cum >= k) {
                        shJ = (unsigned)b;
                        shRemJ = (unsigned)(k - (cum - (long long)u.b.hist[b]));
                        break;
                    }
                }
            }
        }
        __syncthreads();
        const unsigned J = shJ, remJ = shRemJ;

        // single pass: sum softplus over bins > J, gather bin-J values (~8)
        double acc = 0.0;
        for (unsigned i = li; i < cs; i += 16) {
            const float x = ldgF(gseg + i);
            const int b = bin_of_x(x);
            if (b > (int)J) acc += (double)softplus_f(x);
            else if (b == (int)J) {
                unsigned p = atomicAdd(&shCj, 1u);
                if (p < CJCAP) u.b.ubuf[p] = x;
            }
        }
        __syncthreads();
        const unsigned cj = shCj;

        if (cj <= CJCAP) {
            // exact rank-select of top-remJ inside bin J (ties by index)
            for (unsigned i = threadIdx.x; i < cj; i += 256) {
                const float xi = u.b.ubuf[i];
                unsigned r = 0;
                for (unsigned l = 0; l < cj; l++) {
                    const float xl = u.b.ubuf[l];
                    r += (xl > xi || (xl == xi && l < i)) ? 1u : 0u;
                }
                if (r < remJ) acc += (double)softplus_f(xi);
            }
            double t = wredD(acc);
            if (lane == 0) wr[wid] = t;
            __syncthreads();
            if (threadIdx.x == 0)
                stgD((double*)(ws + OFF_NEGSUM) + row, wr[0] + wr[1] + wr[2] + wr[3]);
            donesum = true;
        } else {
            needfb = true;    // pathological mass-tie: fall back to bisection
        }
    }

    if (!donesum && needfb) {
        // exact uint-bisection over the full row (bit-exact threshold);
        // conf/conft are kernel-invariant inputs -> plain cached loads ok
        const float* rowc = conf + row * D_;
        const int*   rowt = conft + row * D_;
        unsigned lo = 0u, hi = 0xFFFFFFFFu;
        for (int it = 0; it < 32; it++) {
            const unsigned mid = lo + ((hi - lo) >> 1);
            unsigned um = (mid & 0x80000000u) ? (mid & 0x7FFFFFFFu) : ~mid;
            float fm = __uint_as_float(um);
            int c = 0;
            for (int i = threadIdx.x; i < D_; i += 256)
                if (rowt[i] <= 0 && rowc[i] > fm) c++;
            const int tot = blockSumI(c, shI);
            if ((long long)tot >= k) lo = mid; else hi = mid;
        }
        unsigned uT = (hi & 0x80000000u) ? (hi & 0x7FFFFFFFu) : ~hi;
        float xT = __uint_as_float(uT);
        int c = 0;
        double acc = 0.0;
        for (int i = threadIdx.x; i < D_; i += 256) {
            if (rowt[i] <= 0) {
                float x = rowc[i];
                if (x > xT) { c++; acc += (double)softplus_f(x); }
            }
        }
        int rem = (int)(k - (long long)blockSumI(c, shI));
        double t = wredD(acc);
        if (lane == 0) wr[wid] = t;
        __syncthreads();
        if (threadIdx.x == 0)
            stgD((double*)(ws + OFF_NEGSUM) + row,
                 wr[0] + wr[1] + wr[2] + wr[3] +
                 (double)rem * (double)softplus_f(xT));
    }

    // ---- done-row election (same drain argument as above)
    __syncthreads();
    if (threadIdx.x == 0) {
        unsigned old = __hip_atomic_fetch_add(
            (unsigned*)(ws + OFF_CNT) + B_, 1u,
            __ATOMIC_RELAXED, __HIP_MEMORY_SCOPE_AGENT);
        shLast = (old == B_ - 1) ? 1 : 0;
    }
    __syncthreads();
    if (!shLast) return;

    // ===================== Phase C: final reduce (was k5) =====================
    {
        const double* sl1p = (const double*)(ws + OFF_SL1P);
        const double* bcep = (const double*)(ws + OFF_BCEP);
        const unsigned* npb = (const unsigned*)(ws + OFF_NP);
        const int* kselp = (const int*)(ws + OFF_KSEL);
        const double* nsp = (const double*)(ws + OFF_NEGSUM);

        double a = 0.0, b2 = 0.0, c2 = 0.0;
        int nn = 0, kk = 0;
        for (int i = threadIdx.x; i < NBLK; i += 256) {
            a += ldgD(sl1p + i); b2 += ldgD(bcep + i); nn += (int)ldgU(npb + i);
        }
        if (threadIdx.x < B_) { kk = ldgI(kselp + threadIdx.x); c2 = ldgD(nsp + threadIdx.x); }

        double ra = wredD(a), rb = wredD(b2), rc = wredD(c2);
        int rn = wredI(nn), rk = wredI(kk);
        if (lane == 0) { wr[wid] = ra; wr[4 + wid] = rb; wrC[wid] = rc; shN[wid] = rn; shK[wid] = rk; }
        __syncthreads();
        if (threadIdx.x == 0) {
            double SL1 = wr[0] + wr[1] + wr[2] + wr[3];
            double BCE = wr[4] + wr[5] + wr[6] + wr[7];
            double NSUM = wrC[0] + wrC[1] + wrC[2] + wrC[3];
            double Np = (double)(shN[0] + shN[1] + shN[2] + shN[3]);
            double Kt = (double)(shK[0] + shK[1] + shK[2] + shK[3]);
            double out0 = (Np > 0.0) ? (SL1 / (4.0 * Np)) / Np : 0.0;
            double denom = Np + Kt;
            double out1 = (Np > 0.0 && denom > 0.0) ? ((BCE + NSUM) / denom) / Np : 0.0;
            out[0] = (float)out0;
            out[1] = (float)out1;
        }
    }
}

extern "C" void kernel_launch(void* const* d_in, const int* in_sizes, int n_in,
                              void* d_out, int out_size, void* d_ws, size_t ws_size,
                              hipStream_t stream)
{
    const float4* loc4  = (const float4*)d_in[0];   // (B,D,4) f32
    const float*  conf  = (const float*)d_in[1];    // (B,D,1) f32
    const float4* loct4 = (const float4*)d_in[2];   // (B,D,4) f32
    const int*    conft = (const int*)d_in[3];      // (B,D)   i32
    unsigned char* ws = (unsigned char*)d_ws;
    float* out = (float*)d_out;

    // zero the 65 election counters (ws is poisoned each iteration)
    hipMemsetAsync(ws + OFF_CNT, 0, (B_ + 1) * sizeof(unsigned), stream);
    mbl_fused<<<dim3(NBLK), dim3(256), 0, stream>>>(loc4, conf, loct4, conft, ws, out);
}